// Round 17
// baseline (1482.984 us; speedup 1.0000x reference)
//
#include <hip/hip_runtime.h>
#include <stdint.h>
#include <stddef.h>

// ---------------------------------------------------------------------------
// SNN policy forward: persistent grouped-GEMM implementation for MI355X.
// B=2048, F=256 (2F=512), H=1024, O=256, T=64.
// Grid: 512 blocks = 32 groups (batch tiles of 64 rows) x 16 h-slices (64 h).
// Block: 256 threads = 4 waves arranged 2(M) x 2(N); wave tile = 32m x 32h,
// v_mfma_f32_32x32x16_f16 with A = spikes {0,1} (exact), B = weights split
// hi/lo f16.  TWO blocks per CU (48 KiB LDS each): barriers/flag-waits
// only couple half the CU's waves; the co-resident block fills stall holes.
// Weight-chunk staging and bits->LDS staging use
// __builtin_amdgcn_global_load_lds (width 16, direct L2->LDS DMA).
// Kept from R13/R15/R16: s_setprio(1/0) around the MFMA cluster (T5),
// chunk-0 prefetch before the flag poll, v_perm A-fragment build
// (byte-replicate + bit-pair expand), imm-offset stage_chunk, vectorized
// k_prep.
// NEW vs R16 (bit-identical result, one barrier removed): the P-combine
// writes nj=0 and nj=1 partials to DISJOINT LDS tiles (PlA/PlB, both inside
// the former bits-alias region) instead of a serialized read-modify-write.
// One barrier (was two) orders {all Pl writes + all vmcnt drains} before
// {flag publish + readout}.  Readout computes P = frn_add(PlA, PlB) — the
// SAME operands in the SAME order as the old RMW -> bit-identical P.
// Synchronization: free-running producer/consumer flags (NO global barrier).
// Ring data uses AGENT-scope relaxed atomic stores; per-(t,group,writer)
// flag published after s_waitcnt vmcnt(0) + __syncthreads.
// All arithmetic (encoder, A values, MFMA order, LIF update, readout) is
// element-identical to the R2/R9 kernel (absmax canary: 0.001953125).
// ---------------------------------------------------------------------------

typedef _Float16 v8h  __attribute__((ext_vector_type(8)));
typedef float    v16f __attribute__((ext_vector_type(16)));

// workspace layout (bytes)
#define OFF_WSTM  0ull                 // main W tiles [hb16][c24][p2][64][72] f16 = 7,077,888
#define OFF_WSTO  7077888ull           // w_out tiles  [hb16][cz16][kc4][q2][32][8] f16 = 1,048,576
#define OFF_BITS  8262656ull           // u32 ring [64][48][2048] col-major = 25,165,824
#define OFF_FLAG  33428480ull          // u32 flags [64][32 group][16 writer] = 131,072

#define SLOT_U32  (48*2048)

__device__ __forceinline__ float frn_add(float a, float b){ return __fadd_rn(a,b); }
__device__ __forceinline__ float frn_sub(float a, float b){ return __fsub_rn(a,b); }
__device__ __forceinline__ float frn_mul(float a, float b){ return __fmul_rn(a,b); }

// direct global->LDS DMA, 16 B per lane; LDS dest = wave-uniform base + lane*16
typedef __attribute__((address_space(1))) const uint32_t gas_u32;
typedef __attribute__((address_space(3))) uint32_t las_u32;
__device__ __forceinline__ void gload_lds16(const void* g, void* l) {
    __builtin_amdgcn_global_load_lds((gas_u32*)g, (las_u32*)l, 16, 0, 0);
}

// ---------------------------------------------------------------------------
// prep kernel: tile/convert weights to hi/lo f16, zero slot0 + flags
// (vectorized: identical per-element conversions, uint4-packed stores)
// ---------------------------------------------------------------------------
__global__ void k_prep(const float* __restrict__ w_in, const float* __restrict__ w_rec,
                       const float* __restrict__ w_out, uint8_t* __restrict__ ws)
{
    const long long stride = (long long)gridDim.x * blockDim.x;
    const long long id = (long long)blockIdx.x * blockDim.x + threadIdx.x;

    // main W tiles [hb16][c24][p2][64][72]: one thread per (hb,c,p,hrow) row.
    if (id < 16LL*24*2*64) {
        _Float16* wm = (_Float16*)(ws + OFF_WSTM);
        int hrow = (int)(id & 63);
        long long t2 = id >> 6;
        int p = (int)(t2 & 1); t2 >>= 1;
        int c = (int)(t2 % 24); int hb = (int)(t2 / 24);
        int h = hb * 64 + hrow;
        const float* src = (c < 8) ? (w_in  + (size_t)h * 512  + c * 64)
                                   : (w_rec + (size_t)h * 1024 + (c - 8) * 64);
        _Float16* dst = wm + (size_t)id * 72;
#pragma unroll 1
        for (int j9 = 0; j9 < 8; ++j9) {
            union { _Float16 h8[8]; uint4 u; } pk;
#pragma unroll
            for (int j = 0; j < 8; ++j) {
                float wv = src[j9 * 8 + j];
                _Float16 hi = (_Float16)wv;
                pk.h8[j] = p ? (_Float16)(wv - (float)hi) : hi;
            }
            *(uint4*)(dst + j9 * 8) = pk.u;
        }
        uint4 z4 = {};
        *(uint4*)(dst + 64) = z4;
    }

    // w_out tiles [hb16][cz16][kc4][q2][col32][j8]: one uint4 (8 f16) per thread.
    if (id < 16LL*16*2048/8) {
        _Float16* wo = (_Float16*)(ws + OFF_WSTO);
        int id2 = (int)id;
        int col = id2 & 31;
        int qq  = (id2 >> 5) & 1;
        int kc  = (id2 >> 6) & 3;
        int cz  = (id2 >> 8) & 15;
        int hbv = id2 >> 12;
        int kbase = cz * 64 + kc * 16 + qq * 8;
        int o = hbv * 16 + (col & 15);
        const float* src = w_out + (size_t)o * 1024 + kbase;
        union { _Float16 h8[8]; uint4 u; } pk;
#pragma unroll
        for (int j = 0; j < 8; ++j) {
            float wv = src[j];
            _Float16 hi = (_Float16)wv;
            pk.h8[j] = (col < 16) ? hi : (_Float16)(wv - (float)hi);
        }
        *(uint4*)(wo + (size_t)id2 * 8) = pk.u;
    }

    uint32_t* bz = (uint32_t*)(ws + OFF_BITS);
    for (long long i = id; i < SLOT_U32; i += stride) bz[i] = 0u;   // slot 0 (enc(0) overwritten, z(-1)=0)
    uint32_t* fl = (uint32_t*)(ws + OFF_FLAG);
    for (long long i = id; i < 64*32*16; i += stride) fl[i] = 0u;
}

// ---------------------------------------------------------------------------
// main persistent kernel
// ---------------------------------------------------------------------------
__global__ __launch_bounds__(256, 2)
void k_snn(const float* __restrict__ x, uint8_t* __restrict__ ws,
           float* __restrict__ outm, const int* __restrict__ seqp)
{
    extern __shared__ uint8_t smem[];
    // smem layout: [0, 36864)      : B stage, 2 slots x [p2][64][72] f16
    //              [36864, 49152)  : bits LDS [48 col][64 row] u32 (12288 B)
    //                                aliased by PlA [64][17] f32 (4352 B) at
    //                                +0 and PlB [64][17] f32 at +4352

    const int tid  = threadIdx.x;
    const int lane = tid & 63;
    const int wv4  = tid >> 6;        // wave id 0..3
    const int mi   = wv4 >> 1;        // M half (32 rows)
    const int nj   = wv4 & 1;         // N half (32 h)
    const int q    = lane >> 5;       // k-octet half
    const int ln   = lane & 31;

    const int b  = blockIdx.x;
    const int bb = b >> 4;                                 // group / 64-row batch tile (0..31)
    const int hb = ((b & 7) << 1) | ((b >> 3) & 1);        // h-slice, XCD-local pairs
    const int rowBase = bb * 64;

    int T = *seqp; if (T > 64) T = 64; if (T < 1) T = 1;

    // readout ownership: o column oo (local 0..15), rows rg*4..rg*4+3
    const int oo = tid & 15;
    const int rg = tid >> 4;          // 0..15

    // perm selectors for byte-replication: byte index q + 2*(kc&1),
    // replicated into all 4 selector bytes (both perm sources = wb).
    const uint32_t selE = q ? 0x01010101u : 0x00000000u;
    const uint32_t selO = selE | 0x02020202u;

    float io4[4], vo4[4], mx4[4];
#pragma unroll
    for (int i = 0; i < 4; ++i) { io4[i] = 0.f; vo4[i] = 0.f; mx4[i] = 0.f; }

    v16f zv;
#pragma unroll
    for (int k = 0; k < 16; ++k) zv[k] = 0.f;
    v16f vS = zv, iS = zv;

    // encoder state: threads 0..127 own one row x 16 features
    float ve[16], cc[16];
    if (tid < 128) {
        const float* xr = x + (size_t)(rowBase + (tid >> 1)) * 256;
        const int f0 = (hb & 7) * 32 + (tid & 1) * 16;
        const float sgn = (hb < 8) ? 50.0f : -50.0f;
        const float4* x4 = (const float4*)(xr + f0);
#pragma unroll
        for (int g2 = 0; g2 < 4; ++g2) {
            float4 cv = x4[g2];
            cc[g2*4+0] = fmaxf(frn_mul(sgn, cv.x), 0.0f);
            cc[g2*4+1] = fmaxf(frn_mul(sgn, cv.y), 0.0f);
            cc[g2*4+2] = fmaxf(frn_mul(sgn, cv.z), 0.0f);
            cc[g2*4+3] = fmaxf(frn_mul(sgn, cv.w), 0.0f);
        }
#pragma unroll
        for (int f = 0; f < 16; ++f) ve[f] = 0.0f;
    }

    uint32_t* const ring  = (uint32_t*)(ws + OFF_BITS);
    uint32_t* const bitsL = (uint32_t*)(smem + 36864);
    uint32_t* const flags = (uint32_t*)(ws + OFF_FLAG);
    const uint8_t* const wchunks = ws + OFF_WSTM + (size_t)hb * 24 * 18432;  // 24 x 18432 B
    uint8_t* const BsB = (uint8_t*)smem;

    // agent-scope relaxed store: write-through past the XCD L2, no wbl2.
    auto st_agent = [](uint32_t* p, uint32_t v) {
        __hip_atomic_store(p, v, __ATOMIC_RELAXED, __HIP_MEMORY_SCOPE_AGENT);
    };

    auto enc_step = [&](int dstSlot) {
        if (tid < 128) {
            uint32_t wd = 0;
#pragma unroll
            for (int f = 0; f < 16; ++f) {
                float vv = ve[f];
                vv = frn_add(vv, frn_mul(0.1f, frn_add(frn_sub(0.0f, vv), cc[f])));
                bool zz = frn_sub(vv, 1.0f) > 0.0f;
                ve[f] = zz ? 0.0f : vv;
                wd |= zz ? (1u << f) : 0u;
            }
            uint32_t other = __shfl_xor(wd, 1);
            if ((tid & 1) == 0)
                st_agent(&ring[(size_t)dstSlot * SLOT_U32 + (size_t)hb * 2048 + rowBase + (tid >> 1)],
                         wd | (other << 16));
        }
    };

    auto flag_pub = [&](int t) {
        if (tid == 0)
            st_agent(&flags[((size_t)t * 32 + bb) * 16 + hb], 1u);
    };

    // stage one 18432-B weight chunk into LDS buffer buf via global_load_lds.
    // Identity copy; wave w covers bytes [w*4096,(w+1)*4096) with FOUR DMAs
    // from ONE base (+1024/2048/3072 fold into the 13-bit global imm offset),
    // waves 0/1 cover the 2 KB tail.  LDS dest = wave-uniform base + lane*16.
    auto stage_chunk = [&](int c, int buf) {
        const uint8_t* gsrc = wchunks + (size_t)c * 18432 + wv4 * 4096 + (size_t)(lane * 16);
        uint8_t* ldst = BsB + buf * 18432 + wv4 * 4096;
        gload_lds16(gsrc,        ldst);
        gload_lds16(gsrc + 1024, ldst + 1024);
        gload_lds16(gsrc + 2048, ldst + 2048);
        gload_lds16(gsrc + 3072, ldst + 3072);
        if (wv4 < 2) {
            const int tail = 16384 - wv4 * 4096 + wv4 * 1024;   // 16384 (w0) / 13312 (w1)
            gload_lds16(gsrc + tail, ldst + tail);
        }
    };

    // ---- publish slot 0 (encoder t=0; z(-1)=0 from k_prep) ----
    enc_step(0);
    asm volatile("s_waitcnt vmcnt(0)" ::: "memory");
    __syncthreads();
    flag_pub(0);
    // prefetch chunk 0 for step 0: flies during the first flag poll; the
    // post-poll __syncthreads (vmcnt(0) drain) guarantees completion.
    stage_chunk(0, 0);

    for (int t = 0; t < T; ++t) {
        // ---- wait for all 16 producers of this group's slot t ----
        if (tid < 16) {
            uint32_t* f = &flags[((size_t)t * 32 + bb) * 16 + tid];
            while (__hip_atomic_load(f, __ATOMIC_RELAXED, __HIP_MEMORY_SCOPE_AGENT) == 0u)
                __builtin_amdgcn_s_sleep(1);
        }
        __syncthreads();

        // ---- slot t bits -> LDS [48 col][64 row] via global_load_lds ----
        // 12 segments of 1024 B; wave w owns segments {w, w+4, w+8}
        // (chunk 0 was prefetched before the poll)
        {
            const uint8_t* srcB = (const uint8_t*)(ring + (size_t)t * SLOT_U32);
#pragma unroll
            for (int s3 = 0; s3 < 3; ++s3) {
                int seg = wv4 + s3 * 4;
                int idx = seg * 64 + lane;                 // uint4 index 0..767
                int col = idx >> 4, within = idx & 15;
                gload_lds16(srcB + ((size_t)col * 512 + (rowBase >> 2) + within) * 16,
                            (uint8_t*)bitsL + (size_t)seg * 1024);
            }
        }
        __syncthreads();   // drains vmcnt: bits + prefetched chunk0 visible

        v16f acc = zv, oacc = zv;

        for (int c = 0; c < 24; ++c) {
            if (c < 23) stage_chunk(c + 1, (c + 1) & 1);   // direct-to-LDS, overlaps MFMA
            const int cz = c - 8;
            const bool duty = (c >= 8) && ((cz & 1) == nj);
            uint4 wof[4];
            if (duty) {
                const _Float16* woc = (const _Float16*)(ws + OFF_WSTO)
                                      + (size_t)(hb * 16 + cz) * 2048;
#pragma unroll
                for (int kc = 0; kc < 4; ++kc)
                    wof[kc] = *(const uint4*)(woc + (size_t)(kc * 2 + q) * 256 + ln * 8);
            }

            const _Float16* Bt = (const _Float16*)(BsB + (c & 1) * 18432);
            uint32_t wb = 0;
            // T5: prioritize this wave through the MFMA cluster; the
            // co-resident block's staging/barrier waves yield issue slots.
            __builtin_amdgcn_s_setprio(1);
#pragma unroll
            for (int kc = 0; kc < 4; ++kc) {
                if ((kc & 1) == 0)
                    wb = bitsL[(c * 2 + (kc >> 1)) * 64 + mi * 32 + ln];
                // A-fragment via v_perm: replicate byte q+2*(kc&1) of wb
                // (rep == t8*0x01010101), then expand bit pairs to the exact
                // {bit0->0x3C00 | bit1->0x3C000000} words.  Bit-identical to
                // the cndmask construction.  Same operand for both perm
                // sources -> operand-order-immune.
                const uint32_t rep = __builtin_amdgcn_perm(wb, wb, (kc & 1) ? selO : selE);
                const uint32_t PC  = 0x003C3C00u;
                union { uint32_t u[4]; v8h h; } ua;
                ua.u[0] = __builtin_amdgcn_perm(PC, PC,  rep       & 0x02000100u);
                ua.u[1] = __builtin_amdgcn_perm(PC, PC, (rep >> 2) & 0x02000100u);
                ua.u[2] = __builtin_amdgcn_perm(PC, PC, (rep >> 4) & 0x02000100u);
                ua.u[3] = __builtin_amdgcn_perm(PC, PC, (rep >> 6) & 0x02000100u);
                const _Float16* brow = Bt + (size_t)(nj * 32 + ln) * 72 + kc * 16 + q * 8;
                v8h Bh = *(const v8h*)brow;
                v8h Bl = *(const v8h*)(brow + 64 * 72);
                // same accumulation order as R2 -> bitwise-identical i
                acc = __builtin_amdgcn_mfma_f32_32x32x16_f16(ua.h, Bh, acc, 0, 0, 0);
                acc = __builtin_amdgcn_mfma_f32_32x32x16_f16(ua.h, Bl, acc, 0, 0, 0);
                if (duty) {
                    union { uint4 u; v8h h; } bo; bo.u = wof[kc];
                    oacc = __builtin_amdgcn_mfma_f32_32x32x16_f16(ua.h, bo.h, oacc, 0, 0, 0);
                }
            }
            __builtin_amdgcn_s_setprio(0);
            __syncthreads();   // drains vmcnt: chunk c+1 complete in LDS
        }

        // ---- hidden state update + spike bit pack (identical arithmetic) ----
        uint32_t zw = 0;
#pragma unroll
        for (int r = 0; r < 16; ++r) {
            float iold = iS[r];
            float vd = frn_add(vS[r], frn_mul(0.1f, frn_add(frn_sub(0.0f, vS[r]), iold)));
            bool z = frn_sub(vd, 1.0f) > 0.0f;
            vS[r] = z ? 0.0f : vd;
            float idc = frn_sub(iold, frn_mul(0.2f, iold));
            iS[r] = frn_add(idc, acc[r]);
            unsigned long long bal = __ballot(z);
            int ra = (r & 3) + ((r >> 2) << 3);
            if (lane == ra)     zw = (uint32_t)bal;
            if (lane == ra + 4) zw = (uint32_t)(bal >> 32);
        }
        const bool publish = (t < T - 1);
        if (publish) {
            if (lane < 32)
                st_agent(&ring[(size_t)(t + 1) * SLOT_U32 + (size_t)(16 + hb * 2 + nj) * 2048
                               + rowBase + mi * 32 + lane], zw);
            enc_step(t + 1);
            // drain our data stores so the flag (published after the next
            // __syncthreads) cannot pass them.
            asm volatile("s_waitcnt vmcnt(0)" ::: "memory");
        }

        // ---- combine readout partials: split PlA/PlB, ONE barrier ----
        {
            // fold lo columns (16..31) into hi columns (0..15)
            float pfold[16];
#pragma unroll
            for (int r = 0; r < 16; ++r)
                pfold[r] = frn_add(oacc[r], __shfl_xor(oacc[r], 16));

            float* const PlA = (float*)(smem + 36864);
            float* const PlB = (float*)(smem + 36864 + 4352);
            float* const Pw  = nj ? PlB : PlA;   // disjoint per-wave targets
#pragma unroll
            for (int r = 0; r < 16; ++r) {
                int rl = mi * 32 + (r & 3) + ((r >> 2) << 3) + (q << 2);
                if (ln < 16) Pw[rl * 17 + ln] = pfold[r];
            }
            __syncthreads();   // all Pl writes visible; all wave drains done
            if (publish) flag_pub(t + 1);

            // ---- readout: vo(t-1) then io(t-1) = 0.8*io(t-2) + P(t-1) ----
            // P = frn_add(PlA, PlB): same operands, same order as the old
            // LDS read-modify-write -> bit-identical P.
            if (t >= 1) {
#pragma unroll
                for (int i = 0; i < 4; ++i) {
                    float P = frn_add(PlA[(rg * 4 + i) * 17 + oo],
                                      PlB[(rg * 4 + i) * 17 + oo]);
                    vo4[i] = frn_add(vo4[i], frn_mul(0.1f, frn_sub(io4[i], vo4[i])));
                    mx4[i] = fmaxf(mx4[i], vo4[i]);
                    float iod = frn_sub(io4[i], frn_mul(0.2f, io4[i]));
                    io4[i] = frn_add(iod, P);
                }
            }
            // prefetch next step's chunk 0 (weights, t-invariant): buffer 0
            // is dead (chunk 22 consumed) and disjoint from the PlA/PlB/bits
            // region read above.  Flies during the next flag poll; drained
            // by the post-poll __syncthreads.
            if (publish) stage_chunk(0, 0);
        }
        // next iter's flag-wait __syncthreads orders the PlA/PlB reads
        // before the next bits DMA overwrites the aliased region
    }

    // ---- epilogue: vo(T-1) + final max, write per-row max voltages ----
#pragma unroll
    for (int i = 0; i < 4; ++i) {
        vo4[i] = frn_add(vo4[i], frn_mul(0.1f, frn_sub(io4[i], vo4[i])));
        mx4[i] = fmaxf(mx4[i], vo4[i]);
        outm[(size_t)(rowBase + rg * 4 + i) * 256 + hb * 16 + oo] = mx4[i];
    }
}

// ---------------------------------------------------------------------------
// softmax over O=256, in-place on d_out
// ---------------------------------------------------------------------------
__global__ void k_sm(float* __restrict__ o)
{
    const int lane = threadIdx.x & 63;
    const int wv4 = threadIdx.x >> 6;
    const int row = blockIdx.x * 8 + wv4 * 2 + (lane >> 5);
    const int ln = lane & 31;
    float* pr = o + (size_t)row * 256;
    float v[8];
#pragma unroll
    for (int i = 0; i < 8; ++i) v[i] = pr[ln + i * 32];
    float m = v[0];
#pragma unroll
    for (int i = 1; i < 8; ++i) m = fmaxf(m, v[i]);
#pragma unroll
    for (int off = 16; off; off >>= 1) m = fmaxf(m, __shfl_xor(m, off, 32));
    float s = 0.f;
#pragma unroll
    for (int i = 0; i < 8; ++i) { v[i] = expf(v[i] - m); s += v[i]; }
#pragma unroll
    for (int off = 16; off; off >>= 1) s += __shfl_xor(s, off, 32);
#pragma unroll
    for (int i = 0; i < 8; ++i) pr[ln + i * 32] = v[i] / s;
}

// ---------------------------------------------------------------------------
extern "C" void kernel_launch(void* const* d_in, const int* in_sizes, int n_in,
                              void* d_out, int out_size, void* d_ws, size_t ws_size,
                              hipStream_t stream)
{
    const float* x     = (const float*)d_in[0];
    const float* w_in  = (const float*)d_in[1];
    const float* w_rec = (const float*)d_in[2];
    const float* w_out = (const float*)d_in[3];
    const int*   seq   = (const int*)d_in[4];
    uint8_t* ws = (uint8_t*)d_ws;
    float* out = (float*)d_out;

    k_prep<<<1024, 256, 0, stream>>>(w_in, w_rec, w_out, ws);

    // 49152 B dynamic LDS per block -> two blocks co-resident per CU
    // (2 x 48 KiB = 96 KiB < 160 KiB). MUST stay under the 64 KiB per-WG
    // dispatch limit (over-requesting silently rejects the launch).
    k_snn<<<512, 256, 49152, stream>>>(x, ws, out, seq);
    k_sm<<<256, 256, 0, stream>>>(out);
}

// Round 18
// 1426.358 us; speedup vs baseline: 1.0397x; 1.0397x over previous
//
#include <hip/hip_runtime.h>
#include <stdint.h>
#include <stddef.h>

// ---------------------------------------------------------------------------
// SNN policy forward: persistent grouped-GEMM implementation for MI355X.
// B=2048, F=256 (2F=512), H=1024, O=256, T=64.
// Grid: 512 blocks = 32 groups (batch tiles of 64 rows) x 16 h-slices (64 h).
// Block: 256 threads = 4 waves arranged 2(M) x 2(N); wave tile = 32m x 32h,
// v_mfma_f32_32x32x16_f16 with A = spikes {0,1} (exact), B = weights split
// hi/lo f16.  TWO blocks per CU (48 KiB LDS each): barriers/flag-waits
// only couple half the CU's waves; the co-resident block fills stall holes.
// Weight-chunk staging and bits->LDS staging use
// __builtin_amdgcn_global_load_lds (width 16, direct L2->LDS DMA).
// Kept from R13/R15/R16: s_setprio(1/0) around the MFMA cluster (T5), chunk-0
// prefetch before the flag poll, v_perm A-fragment build (byte-replicate +
// bit-pair expand), imm-offset stage_chunk, vectorized k_prep.
// R17's split-PlA/PlB combine REVERTED: it doubled LDS bank conflicts
// (readout had to sweep two *17-stride tiles) and regressed 4%.  This is
// the R16 configuration — the fastest verified kernel of the session.
// Synchronization: free-running producer/consumer flags (NO global barrier).
// Ring data uses AGENT-scope relaxed atomic stores; per-(t,group,writer)
// flag published after s_waitcnt vmcnt(0) + __syncthreads.
// All arithmetic (encoder, A values, MFMA order, LIF update, readout) is
// element-identical to the R2/R9 kernel (absmax canary: 0.001953125).
// ---------------------------------------------------------------------------

typedef _Float16 v8h  __attribute__((ext_vector_type(8)));
typedef float    v16f __attribute__((ext_vector_type(16)));

// workspace layout (bytes)
#define OFF_WSTM  0ull                 // main W tiles [hb16][c24][p2][64][72] f16 = 7,077,888
#define OFF_WSTO  7077888ull           // w_out tiles  [hb16][cz16][kc4][q2][32][8] f16 = 1,048,576
#define OFF_BITS  8262656ull           // u32 ring [64][48][2048] col-major = 25,165,824
#define OFF_FLAG  33428480ull          // u32 flags [64][32 group][16 writer] = 131,072

#define SLOT_U32  (48*2048)

__device__ __forceinline__ float frn_add(float a, float b){ return __fadd_rn(a,b); }
__device__ __forceinline__ float frn_sub(float a, float b){ return __fsub_rn(a,b); }
__device__ __forceinline__ float frn_mul(float a, float b){ return __fmul_rn(a,b); }

// direct global->LDS DMA, 16 B per lane; LDS dest = wave-uniform base + lane*16
typedef __attribute__((address_space(1))) const uint32_t gas_u32;
typedef __attribute__((address_space(3))) uint32_t las_u32;
__device__ __forceinline__ void gload_lds16(const void* g, void* l) {
    __builtin_amdgcn_global_load_lds((gas_u32*)g, (las_u32*)l, 16, 0, 0);
}

// ---------------------------------------------------------------------------
// prep kernel: tile/convert weights to hi/lo f16, zero slot0 + flags
// (vectorized: identical per-element conversions, uint4-packed stores)
// ---------------------------------------------------------------------------
__global__ void k_prep(const float* __restrict__ w_in, const float* __restrict__ w_rec,
                       const float* __restrict__ w_out, uint8_t* __restrict__ ws)
{
    const long long stride = (long long)gridDim.x * blockDim.x;
    const long long id = (long long)blockIdx.x * blockDim.x + threadIdx.x;

    // main W tiles [hb16][c24][p2][64][72]: one thread per (hb,c,p,hrow) row.
    if (id < 16LL*24*2*64) {
        _Float16* wm = (_Float16*)(ws + OFF_WSTM);
        int hrow = (int)(id & 63);
        long long t2 = id >> 6;
        int p = (int)(t2 & 1); t2 >>= 1;
        int c = (int)(t2 % 24); int hb = (int)(t2 / 24);
        int h = hb * 64 + hrow;
        const float* src = (c < 8) ? (w_in  + (size_t)h * 512  + c * 64)
                                   : (w_rec + (size_t)h * 1024 + (c - 8) * 64);
        _Float16* dst = wm + (size_t)id * 72;
#pragma unroll 1
        for (int j9 = 0; j9 < 8; ++j9) {
            union { _Float16 h8[8]; uint4 u; } pk;
#pragma unroll
            for (int j = 0; j < 8; ++j) {
                float wv = src[j9 * 8 + j];
                _Float16 hi = (_Float16)wv;
                pk.h8[j] = p ? (_Float16)(wv - (float)hi) : hi;
            }
            *(uint4*)(dst + j9 * 8) = pk.u;
        }
        uint4 z4 = {};
        *(uint4*)(dst + 64) = z4;
    }

    // w_out tiles [hb16][cz16][kc4][q2][col32][j8]: one uint4 (8 f16) per thread.
    if (id < 16LL*16*2048/8) {
        _Float16* wo = (_Float16*)(ws + OFF_WSTO);
        int id2 = (int)id;
        int col = id2 & 31;
        int qq  = (id2 >> 5) & 1;
        int kc  = (id2 >> 6) & 3;
        int cz  = (id2 >> 8) & 15;
        int hbv = id2 >> 12;
        int kbase = cz * 64 + kc * 16 + qq * 8;
        int o = hbv * 16 + (col & 15);
        const float* src = w_out + (size_t)o * 1024 + kbase;
        union { _Float16 h8[8]; uint4 u; } pk;
#pragma unroll
        for (int j = 0; j < 8; ++j) {
            float wv = src[j];
            _Float16 hi = (_Float16)wv;
            pk.h8[j] = (col < 16) ? hi : (_Float16)(wv - (float)hi);
        }
        *(uint4*)(wo + (size_t)id2 * 8) = pk.u;
    }

    uint32_t* bz = (uint32_t*)(ws + OFF_BITS);
    for (long long i = id; i < SLOT_U32; i += stride) bz[i] = 0u;   // slot 0 (enc(0) overwritten, z(-1)=0)
    uint32_t* fl = (uint32_t*)(ws + OFF_FLAG);
    for (long long i = id; i < 64*32*16; i += stride) fl[i] = 0u;
}

// ---------------------------------------------------------------------------
// main persistent kernel
// ---------------------------------------------------------------------------
__global__ __launch_bounds__(256, 2)
void k_snn(const float* __restrict__ x, uint8_t* __restrict__ ws,
           float* __restrict__ outm, const int* __restrict__ seqp)
{
    extern __shared__ uint8_t smem[];
    // smem layout: [0, 36864)      : B stage, 2 slots x [p2][64][72] f16
    //              [36864, 49152)  : bits LDS [48 col][64 row] u32 (12288 B)
    //                                aliased by P-tile [64][17] f32 (4352 B)

    const int tid  = threadIdx.x;
    const int lane = tid & 63;
    const int wv4  = tid >> 6;        // wave id 0..3
    const int mi   = wv4 >> 1;        // M half (32 rows)
    const int nj   = wv4 & 1;         // N half (32 h)
    const int q    = lane >> 5;       // k-octet half
    const int ln   = lane & 31;

    const int b  = blockIdx.x;
    const int bb = b >> 4;                                 // group / 64-row batch tile (0..31)
    const int hb = ((b & 7) << 1) | ((b >> 3) & 1);        // h-slice, XCD-local pairs
    const int rowBase = bb * 64;

    int T = *seqp; if (T > 64) T = 64; if (T < 1) T = 1;

    // readout ownership: o column oo (local 0..15), rows rg*4..rg*4+3
    const int oo = tid & 15;
    const int rg = tid >> 4;          // 0..15

    // perm selectors for byte-replication: byte index q + 2*(kc&1),
    // replicated into all 4 selector bytes (both perm sources = wb).
    const uint32_t selE = q ? 0x01010101u : 0x00000000u;
    const uint32_t selO = selE | 0x02020202u;

    float io4[4], vo4[4], mx4[4];
#pragma unroll
    for (int i = 0; i < 4; ++i) { io4[i] = 0.f; vo4[i] = 0.f; mx4[i] = 0.f; }

    v16f zv;
#pragma unroll
    for (int k = 0; k < 16; ++k) zv[k] = 0.f;
    v16f vS = zv, iS = zv;

    // encoder state: threads 0..127 own one row x 16 features
    float ve[16], cc[16];
    if (tid < 128) {
        const float* xr = x + (size_t)(rowBase + (tid >> 1)) * 256;
        const int f0 = (hb & 7) * 32 + (tid & 1) * 16;
        const float sgn = (hb < 8) ? 50.0f : -50.0f;
        const float4* x4 = (const float4*)(xr + f0);
#pragma unroll
        for (int g2 = 0; g2 < 4; ++g2) {
            float4 cv = x4[g2];
            cc[g2*4+0] = fmaxf(frn_mul(sgn, cv.x), 0.0f);
            cc[g2*4+1] = fmaxf(frn_mul(sgn, cv.y), 0.0f);
            cc[g2*4+2] = fmaxf(frn_mul(sgn, cv.z), 0.0f);
            cc[g2*4+3] = fmaxf(frn_mul(sgn, cv.w), 0.0f);
        }
#pragma unroll
        for (int f = 0; f < 16; ++f) ve[f] = 0.0f;
    }

    uint32_t* const ring  = (uint32_t*)(ws + OFF_BITS);
    uint32_t* const bitsL = (uint32_t*)(smem + 36864);
    uint32_t* const flags = (uint32_t*)(ws + OFF_FLAG);
    const uint8_t* const wchunks = ws + OFF_WSTM + (size_t)hb * 24 * 18432;  // 24 x 18432 B
    uint8_t* const BsB = (uint8_t*)smem;

    // agent-scope relaxed store: write-through past the XCD L2, no wbl2.
    auto st_agent = [](uint32_t* p, uint32_t v) {
        __hip_atomic_store(p, v, __ATOMIC_RELAXED, __HIP_MEMORY_SCOPE_AGENT);
    };

    auto enc_step = [&](int dstSlot) {
        if (tid < 128) {
            uint32_t wd = 0;
#pragma unroll
            for (int f = 0; f < 16; ++f) {
                float vv = ve[f];
                vv = frn_add(vv, frn_mul(0.1f, frn_add(frn_sub(0.0f, vv), cc[f])));
                bool zz = frn_sub(vv, 1.0f) > 0.0f;
                ve[f] = zz ? 0.0f : vv;
                wd |= zz ? (1u << f) : 0u;
            }
            uint32_t other = __shfl_xor(wd, 1);
            if ((tid & 1) == 0)
                st_agent(&ring[(size_t)dstSlot * SLOT_U32 + (size_t)hb * 2048 + rowBase + (tid >> 1)],
                         wd | (other << 16));
        }
    };

    auto flag_pub = [&](int t) {
        if (tid == 0)
            st_agent(&flags[((size_t)t * 32 + bb) * 16 + hb], 1u);
    };

    // stage one 18432-B weight chunk into LDS buffer buf via global_load_lds.
    // Identity copy; wave w covers bytes [w*4096,(w+1)*4096) with FOUR DMAs
    // from ONE base (+1024/2048/3072 fold into the 13-bit global imm offset),
    // waves 0/1 cover the 2 KB tail.  LDS dest = wave-uniform base + lane*16.
    auto stage_chunk = [&](int c, int buf) {
        const uint8_t* gsrc = wchunks + (size_t)c * 18432 + wv4 * 4096 + (size_t)(lane * 16);
        uint8_t* ldst = BsB + buf * 18432 + wv4 * 4096;
        gload_lds16(gsrc,        ldst);
        gload_lds16(gsrc + 1024, ldst + 1024);
        gload_lds16(gsrc + 2048, ldst + 2048);
        gload_lds16(gsrc + 3072, ldst + 3072);
        if (wv4 < 2) {
            const int tail = 16384 - wv4 * 4096 + wv4 * 1024;   // 16384 (w0) / 13312 (w1)
            gload_lds16(gsrc + tail, ldst + tail);
        }
    };

    // ---- publish slot 0 (encoder t=0; z(-1)=0 from k_prep) ----
    enc_step(0);
    asm volatile("s_waitcnt vmcnt(0)" ::: "memory");
    __syncthreads();
    flag_pub(0);
    // prefetch chunk 0 for step 0: flies during the first flag poll; the
    // post-poll __syncthreads (vmcnt(0) drain) guarantees completion.
    stage_chunk(0, 0);

    for (int t = 0; t < T; ++t) {
        // ---- wait for all 16 producers of this group's slot t ----
        if (tid < 16) {
            uint32_t* f = &flags[((size_t)t * 32 + bb) * 16 + tid];
            while (__hip_atomic_load(f, __ATOMIC_RELAXED, __HIP_MEMORY_SCOPE_AGENT) == 0u)
                __builtin_amdgcn_s_sleep(1);
        }
        __syncthreads();

        // ---- slot t bits -> LDS [48 col][64 row] via global_load_lds ----
        // 12 segments of 1024 B; wave w owns segments {w, w+4, w+8}
        // (chunk 0 was prefetched before the poll)
        {
            const uint8_t* srcB = (const uint8_t*)(ring + (size_t)t * SLOT_U32);
#pragma unroll
            for (int s3 = 0; s3 < 3; ++s3) {
                int seg = wv4 + s3 * 4;
                int idx = seg * 64 + lane;                 // uint4 index 0..767
                int col = idx >> 4, within = idx & 15;
                gload_lds16(srcB + ((size_t)col * 512 + (rowBase >> 2) + within) * 16,
                            (uint8_t*)bitsL + (size_t)seg * 1024);
            }
        }
        __syncthreads();   // drains vmcnt: bits + prefetched chunk0 visible

        v16f acc = zv, oacc = zv;

        for (int c = 0; c < 24; ++c) {
            if (c < 23) stage_chunk(c + 1, (c + 1) & 1);   // direct-to-LDS, overlaps MFMA
            const int cz = c - 8;
            const bool duty = (c >= 8) && ((cz & 1) == nj);
            uint4 wof[4];
            if (duty) {
                const _Float16* woc = (const _Float16*)(ws + OFF_WSTO)
                                      + (size_t)(hb * 16 + cz) * 2048;
#pragma unroll
                for (int kc = 0; kc < 4; ++kc)
                    wof[kc] = *(const uint4*)(woc + (size_t)(kc * 2 + q) * 256 + ln * 8);
            }

            const _Float16* Bt = (const _Float16*)(BsB + (c & 1) * 18432);
            uint32_t wb = 0;
            // T5: prioritize this wave through the MFMA cluster; the
            // co-resident block's staging/barrier waves yield issue slots.
            __builtin_amdgcn_s_setprio(1);
#pragma unroll
            for (int kc = 0; kc < 4; ++kc) {
                if ((kc & 1) == 0)
                    wb = bitsL[(c * 2 + (kc >> 1)) * 64 + mi * 32 + ln];
                // A-fragment via v_perm: replicate byte q+2*(kc&1) of wb
                // (rep == t8*0x01010101), then expand bit pairs to the exact
                // {bit0->0x3C00 | bit1->0x3C000000} words.  Bit-identical to
                // the cndmask construction.  Same operand for both perm
                // sources -> operand-order-immune.
                const uint32_t rep = __builtin_amdgcn_perm(wb, wb, (kc & 1) ? selO : selE);
                const uint32_t PC  = 0x003C3C00u;
                union { uint32_t u[4]; v8h h; } ua;
                ua.u[0] = __builtin_amdgcn_perm(PC, PC,  rep       & 0x02000100u);
                ua.u[1] = __builtin_amdgcn_perm(PC, PC, (rep >> 2) & 0x02000100u);
                ua.u[2] = __builtin_amdgcn_perm(PC, PC, (rep >> 4) & 0x02000100u);
                ua.u[3] = __builtin_amdgcn_perm(PC, PC, (rep >> 6) & 0x02000100u);
                const _Float16* brow = Bt + (size_t)(nj * 32 + ln) * 72 + kc * 16 + q * 8;
                v8h Bh = *(const v8h*)brow;
                v8h Bl = *(const v8h*)(brow + 64 * 72);
                // same accumulation order as R2 -> bitwise-identical i
                acc = __builtin_amdgcn_mfma_f32_32x32x16_f16(ua.h, Bh, acc, 0, 0, 0);
                acc = __builtin_amdgcn_mfma_f32_32x32x16_f16(ua.h, Bl, acc, 0, 0, 0);
                if (duty) {
                    union { uint4 u; v8h h; } bo; bo.u = wof[kc];
                    oacc = __builtin_amdgcn_mfma_f32_32x32x16_f16(ua.h, bo.h, oacc, 0, 0, 0);
                }
            }
            __builtin_amdgcn_s_setprio(0);
            __syncthreads();   // drains vmcnt: chunk c+1 complete in LDS
        }

        // ---- hidden state update + spike bit pack (identical arithmetic) ----
        uint32_t zw = 0;
#pragma unroll
        for (int r = 0; r < 16; ++r) {
            float iold = iS[r];
            float vd = frn_add(vS[r], frn_mul(0.1f, frn_add(frn_sub(0.0f, vS[r]), iold)));
            bool z = frn_sub(vd, 1.0f) > 0.0f;
            vS[r] = z ? 0.0f : vd;
            float idc = frn_sub(iold, frn_mul(0.2f, iold));
            iS[r] = frn_add(idc, acc[r]);
            unsigned long long bal = __ballot(z);
            int ra = (r & 3) + ((r >> 2) << 3);
            if (lane == ra)     zw = (uint32_t)bal;
            if (lane == ra + 4) zw = (uint32_t)(bal >> 32);
        }
        const bool publish = (t < T - 1);
        if (publish) {
            if (lane < 32)
                st_agent(&ring[(size_t)(t + 1) * SLOT_U32 + (size_t)(16 + hb * 2 + nj) * 2048
                               + rowBase + mi * 32 + lane], zw);
            enc_step(t + 1);
            // drain our data stores so the flag (published after the next
            // __syncthreads) cannot pass them.
            asm volatile("s_waitcnt vmcnt(0)" ::: "memory");
        }

        // ---- combine readout partials in LDS (aliases bits region) ----
        {
            // fold lo columns (16..31) into hi columns (0..15)
            float pfold[16];
#pragma unroll
            for (int r = 0; r < 16; ++r)
                pfold[r] = frn_add(oacc[r], __shfl_xor(oacc[r], 16));

            float* Pl = (float*)(smem + 36864);
            if (nj == 0) {
#pragma unroll
                for (int r = 0; r < 16; ++r) {
                    int rl = mi * 32 + (r & 3) + ((r >> 2) << 3) + (q << 2);
                    if (ln < 16) Pl[rl * 17 + ln] = pfold[r];
                }
            }
            __syncthreads();
            if (publish) flag_pub(t + 1);          // all data stores drained above
            if (nj == 1) {
#pragma unroll
                for (int r = 0; r < 16; ++r) {
                    int rl = mi * 32 + (r & 3) + ((r >> 2) << 3) + (q << 2);
                    if (ln < 16) Pl[rl * 17 + ln] = frn_add(Pl[rl * 17 + ln], pfold[r]);
                }
            }
            __syncthreads();

            // ---- readout: vo(t-1) then io(t-1) = 0.8*io(t-2) + P(t-1) ----
            if (t >= 1) {
#pragma unroll
                for (int i = 0; i < 4; ++i) {
                    float P = Pl[(rg * 4 + i) * 17 + oo];
                    vo4[i] = frn_add(vo4[i], frn_mul(0.1f, frn_sub(io4[i], vo4[i])));
                    mx4[i] = fmaxf(mx4[i], vo4[i]);
                    float iod = frn_sub(io4[i], frn_mul(0.2f, io4[i]));
                    io4[i] = frn_add(iod, P);
                }
            }
            // prefetch next step's chunk 0 (weights, t-invariant): buffer 0
            // is dead (chunk 22 consumed) and disjoint from the Pl/bits
            // region read above.  Flies during the next flag poll; drained
            // by the post-poll __syncthreads.
            if (publish) stage_chunk(0, 0);
        }
        // next iter's flag-wait __syncthreads protects the P-tile/bits alias
    }

    // ---- epilogue: vo(T-1) + final max, write per-row max voltages ----
#pragma unroll
    for (int i = 0; i < 4; ++i) {
        vo4[i] = frn_add(vo4[i], frn_mul(0.1f, frn_sub(io4[i], vo4[i])));
        mx4[i] = fmaxf(mx4[i], vo4[i]);
        outm[(size_t)(rowBase + rg * 4 + i) * 256 + hb * 16 + oo] = mx4[i];
    }
}

// ---------------------------------------------------------------------------
// softmax over O=256, in-place on d_out
// ---------------------------------------------------------------------------
__global__ void k_sm(float* __restrict__ o)
{
    const int lane = threadIdx.x & 63;
    const int wv4 = threadIdx.x >> 6;
    const int row = blockIdx.x * 8 + wv4 * 2 + (lane >> 5);
    const int ln = lane & 31;
    float* pr = o + (size_t)row * 256;
    float v[8];
#pragma unroll
    for (int i = 0; i < 8; ++i) v[i] = pr[ln + i * 32];
    float m = v[0];
#pragma unroll
    for (int i = 1; i < 8; ++i) m = fmaxf(m, v[i]);
#pragma unroll
    for (int off = 16; off; off >>= 1) m = fmaxf(m, __shfl_xor(m, off, 32));
    float s = 0.f;
#pragma unroll
    for (int i = 0; i < 8; ++i) { v[i] = expf(v[i] - m); s += v[i]; }
#pragma unroll
    for (int off = 16; off; off >>= 1) s += __shfl_xor(s, off, 32);
#pragma unroll
    for (int i = 0; i < 8; ++i) pr[ln + i * 32] = v[i] / s;
}

// ---------------------------------------------------------------------------
extern "C" void kernel_launch(void* const* d_in, const int* in_sizes, int n_in,
                              void* d_out, int out_size, void* d_ws, size_t ws_size,
                              hipStream_t stream)
{
    const float* x     = (const float*)d_in[0];
    const float* w_in  = (const float*)d_in[1];
    const float* w_rec = (const float*)d_in[2];
    const float* w_out = (const float*)d_in[3];
    const int*   seq   = (const int*)d_in[4];
    uint8_t* ws = (uint8_t*)d_ws;
    float* out = (float*)d_out;

    k_prep<<<1024, 256, 0, stream>>>(w_in, w_rec, w_out, ws);

    // 49152 B dynamic LDS per block -> two blocks co-resident per CU
    // (2 x 48 KiB = 96 KiB < 160 KiB). MUST stay under the 64 KiB per-WG
    // dispatch limit (over-requesting silently rejects the launch).
    k_snn<<<512, 256, 49152, stream>>>(x, ws, out, seq);
    k_sm<<<256, 256, 0, stream>>>(out);
}